// Round 1
// baseline (353.876 us; speedup 1.0000x reference)
//
#include <hip/hip_runtime.h>
#include <math.h>

// Problem constants (fixed by reference)
#define BB    16384
#define RNN   256
#define LAT   64
#define ATTD  64
#define NA    32
#define HID   256
#define NCOL  384      // HID + LAT + ATT outputs of the fused h-GEMM
#define TBR   32       // rows of B per block
#define HP    257      // padded hbuf leading dim (bank-conflict-free)
#define ZP    385      // padded Z leading dim (385%32==1 -> 2-way alias, free)
#define SLOPE 0.01f

// ws layout (floats):
//   Wt  [256][384]  @ 0        (transposed concat of w1_h | q_fc_w | key_w)
//   V   [32][256]   @ 98304    (AL @ w1_a.T + msg_b1)
//   Qy  [32][64]    @ 106496   (AL @ query_w.T + query_b)
#define WS_WT 0
#define WS_V  98304
#define WS_QY 106496

__global__ __launch_bounds__(256) void prep_kernel(
    const float* __restrict__ AL,       // [32][64]
    const float* __restrict__ q_fc_w,   // [64][256]
    const float* __restrict__ msg_w1,   // [256][320]
    const float* __restrict__ msg_b1,   // [256]
    const float* __restrict__ key_w,    // [64][256]
    const float* __restrict__ query_w,  // [64][64]
    const float* __restrict__ query_b,  // [64]
    float* __restrict__ ws)
{
    const int tid = blockIdx.x * blockDim.x + threadIdx.x;
    const int nth = gridDim.x * blockDim.x;
    float* Wt = ws + WS_WT;
    float* V  = ws + WS_V;
    float* Qy = ws + WS_QY;

    // Transposed fused weight: Wt[k*384 + j]
    for (int idx = tid; idx < 256 * NCOL; idx += nth) {
        const int k = idx / NCOL;
        const int j = idx - k * NCOL;
        float v;
        if (j < 256)      v = msg_w1[j * 320 + k];          // w1_h[j][k]
        else if (j < 320) v = q_fc_w[(j - 256) * 256 + k];  // q_fc_w[j'][k]
        else              v = key_w[(j - 320) * 256 + k];   // key_w[j'][k]
        Wt[idx] = v;
    }
    // V[a][h] = msg_b1[h] + sum_l AL[a][l] * w1_a[h][l]
    for (int idx = tid; idx < NA * HID; idx += nth) {
        const int a = idx >> 8, hc = idx & 255;
        float s = msg_b1[hc];
        #pragma unroll 16
        for (int l = 0; l < LAT; ++l)
            s += AL[a * LAT + l] * msg_w1[hc * 320 + 256 + l];
        V[idx] = s;
    }
    // Qy[a][j] = query_b[j] + sum_l AL[a][l] * query_w[j][l]
    for (int idx = tid; idx < NA * ATTD; idx += nth) {
        const int a = idx >> 6, j = idx & 63;
        float s = query_b[j];
        #pragma unroll 16
        for (int l = 0; l < LAT; ++l)
            s += AL[a * LAT + l] * query_w[j * LAT + l];
        Qy[idx] = s;
    }
}

__global__ __launch_bounds__(512) void main_kernel(
    const float* __restrict__ h,        // [16384][256]
    const float* __restrict__ AL,       // [32][64]
    const float* __restrict__ q_fc_b,   // [64]
    const float* __restrict__ msg_w2,   // [32][256]
    const float* __restrict__ msg_b2,   // [32]
    const float* __restrict__ key_b,    // [64]
    const float* __restrict__ ws,
    float* __restrict__ out)            // [16384][32]
{
    // LDS: region A = hbuf[32][257] (phase 1) then Z[32][385] (phase 2+)
    //      region B = Sc[32][32] scores
    __shared__ float lds[TBR * ZP + TBR * NA];   // 13344 floats = 53376 B
    float* Zl  = lds;
    float* Scl = lds + TBR * ZP;

    const float* Wt = ws + WS_WT;
    const float* Vt = ws + WS_V;
    const float* Qy = ws + WS_QY;

    const int t  = threadIdx.x;
    const int b0 = blockIdx.x * TBR;

    // ---- stage h rows into padded LDS (coalesced float4 loads) ----
    for (int i = t; i < TBR * 64; i += 512) {      // 2048 float4 groups
        const int b  = i >> 6;
        const int kk = (i & 63) << 2;
        const float4 v = *(const float4*)(h + (size_t)(b0 + b) * RNN + kk);
        float* dst = Zl + b * HP + kk;
        dst[0] = v.x; dst[1] = v.y; dst[2] = v.z; dst[3] = v.w;
    }
    __syncthreads();

    // ---- fused GEMM: Z[b][0:384] = h[b] @ Wt  (+ bias on cols >=256) ----
    const int lane    = t & 63;
    const int wave    = t >> 6;
    const int row     = lane & 31;
    const int jbase   = wave * 48 + (lane >> 5) * 24;   // 8 waves x 2 halves x 24 cols
    float acc[24];
    #pragma unroll
    for (int j = 0; j < 24; ++j) acc[j] = 0.f;
    {
        const float* __restrict__ hrow = Zl + row * HP;
        const float* __restrict__ wcol = Wt + jbase;
        for (int k = 0; k < 256; ++k) {
            const float hv = hrow[k];
            #pragma unroll
            for (int j = 0; j < 24; ++j)
                acc[j] += hv * wcol[k * NCOL + j];
        }
    }
    __syncthreads();   // all hbuf reads done before Z overwrites region A
    #pragma unroll
    for (int j = 0; j < 24; ++j) {
        const int jg = jbase + j;
        float bias = 0.f;
        if (jg >= 256) bias = (jg < 320) ? q_fc_b[jg - 256] : key_b[jg - 320];
        Zl[row * ZP + jg] = acc[j] + bias;
    }
    __syncthreads();

    // ---- S[b][h] = sum_a leaky(U[b][h] + V[a][h]), in place over U ----
    for (int idx = t; idx < TBR * HID; idx += 512) {
        const int b = idx >> 8, hc = idx & 255;
        const float u = Zl[b * ZP + hc];
        float s = 0.f;
        #pragma unroll
        for (int a = 0; a < NA; ++a) {
            const float pre = u + Vt[a * HID + hc];
            s += (pre >= 0.f) ? pre : SLOPE * pre;
        }
        Zl[b * ZP + hc] = s;
    }
    __syncthreads();

    // ---- scores[b][a] = (key[b] . Qy[a]) / 8 ----
    for (int idx = t; idx < TBR * NA; idx += 512) {
        const int b = idx >> 5, a = idx & 31;
        const float* keyr = Zl + b * ZP + 320;
        const float* qr   = Qy + a * ATTD;
        float s = 0.f;
        #pragma unroll
        for (int j = 0; j < ATTD; ++j) s += keyr[j] * qr[j];
        Scl[idx] = s * 0.125f;
    }
    __syncthreads();

    // ---- softmax + q + msgsum -> out ----
    for (int idx = t; idx < TBR * NA; idx += 512) {
        const int b = idx >> 5, a = idx & 31;
        const float* srow = Scl + b * NA;
        float mx = -1e30f;
        #pragma unroll
        for (int i = 0; i < NA; ++i) mx = fmaxf(mx, srow[i]);
        float den = 0.f;
        #pragma unroll
        for (int i = 0; i < NA; ++i) den += __expf(srow[i] - mx);
        const float sm = __expf(srow[a] - mx) / den;

        // q[b][a] = role_key[b] . AL[a]
        const float* rk = Zl + b * ZP + 256;
        const float* al = AL + a * LAT;
        float qv = 0.f;
        #pragma unroll
        for (int l = 0; l < LAT; ++l) qv += rk[l] * al[l];

        // msgsum[b][a] = S[b] . msg_w2[a] + 32*msg_b2[a]
        const float* Sr  = Zl + b * ZP;
        const float* w2r = msg_w2 + a * HID;
        float ms = 32.f * msg_b2[a];
        #pragma unroll 8
        for (int k = 0; k < HID; ++k) ms += Sr[k] * w2r[k];

        out[(size_t)(b0 + b) * NA + a] = qv + sm * ms;
    }
}

extern "C" void kernel_launch(void* const* d_in, const int* in_sizes, int n_in,
                              void* d_out, int out_size, void* d_ws, size_t ws_size,
                              hipStream_t stream) {
    const float* h        = (const float*)d_in[0];
    const float* AL       = (const float*)d_in[1];
    const float* q_fc_w   = (const float*)d_in[2];
    const float* q_fc_b   = (const float*)d_in[3];
    const float* msg_w1   = (const float*)d_in[4];
    const float* msg_b1   = (const float*)d_in[5];
    const float* msg_w2   = (const float*)d_in[6];
    const float* msg_b2   = (const float*)d_in[7];
    const float* key_w    = (const float*)d_in[8];
    const float* key_b    = (const float*)d_in[9];
    const float* query_w  = (const float*)d_in[10];
    const float* query_b  = (const float*)d_in[11];
    float* out = (float*)d_out;
    float* ws  = (float*)d_ws;

    prep_kernel<<<96, 256, 0, stream>>>(AL, q_fc_w, msg_w1, msg_b1,
                                        key_w, query_w, query_b, ws);
    main_kernel<<<BB / TBR, 512, 0, stream>>>(h, AL, q_fc_b, msg_w2, msg_b2,
                                              key_b, ws, out);
}

// Round 2
// 184.825 us; speedup vs baseline: 1.9147x; 1.9147x over previous
//
#include <hip/hip_runtime.h>
#include <math.h>

// Problem constants (fixed by reference)
#define BB    16384
#define RNN   256
#define LAT   64
#define ATTD  64
#define NA    32
#define HID   256
#define NCOL  384
#define TBR   32       // rows of B per block
#define KP    264      // padded K-stride (bf16 elems) for hbuf and Wb
#define ZP    388      // Z row stride (floats); 388%4==0 -> 16B-aligned rows
#define SLOPE 0.01f

// ws layout (float units):
//   Wb  bf16[384][264] @ 0       (concat w1_h | q_fc_w | key_w, row-major [col][k])
//   VT  f32 [256][32]  @ 50688   (V transposed: VT[hc][a] = msg_b1[hc] + AL[a].w1_a[hc])
//   Qy  f32 [32][64]   @ 58880   (AL @ query_w.T + query_b)
#define WS_VT 50688
#define WS_QY 58880

typedef __attribute__((ext_vector_type(8))) short bf16x8;
typedef __attribute__((ext_vector_type(4))) float f32x4;
typedef __attribute__((ext_vector_type(8))) unsigned short ushort8;

__device__ __forceinline__ unsigned short f2bf(float x) {
    union { float f; unsigned u; } c; c.f = x;
    unsigned r = c.u + 0x7FFFu + ((c.u >> 16) & 1u);
    return (unsigned short)(r >> 16);
}

__global__ __launch_bounds__(256) void prep_kernel(
    const float* __restrict__ AL,       // [32][64]
    const float* __restrict__ q_fc_w,   // [64][256]
    const float* __restrict__ msg_w1,   // [256][320]
    const float* __restrict__ msg_b1,   // [256]
    const float* __restrict__ key_w,    // [64][256]
    const float* __restrict__ query_w,  // [64][64]
    const float* __restrict__ query_b,  // [64]
    float* __restrict__ ws)
{
    const int tid = blockIdx.x * 256 + threadIdx.x;
    const int nth = gridDim.x * 256;
    unsigned short* Wb = (unsigned short*)ws;
    float* VT = ws + WS_VT;
    float* Qy = ws + WS_QY;

    // Wb[j][k] bf16 — NO transpose needed (MFMA B-frag is n-major = original layout)
    for (int idx = tid; idx < NCOL * 256; idx += nth) {
        const int j = idx >> 8, k = idx & 255;
        float v;
        if (j < 256)      v = msg_w1[j * 320 + k];          // w1_h
        else if (j < 320) v = q_fc_w[(j - 256) * 256 + k];
        else              v = key_w[(j - 320) * 256 + k];
        Wb[j * KP + k] = f2bf(v);
    }
    // VT[hc][a] = msg_b1[hc] + sum_l AL[a][l] * w1_a[hc][l]
    for (int idx = tid; idx < HID * NA; idx += nth) {
        const int hc = idx >> 5, a = idx & 31;
        float s = msg_b1[hc];
        #pragma unroll 16
        for (int l = 0; l < LAT; ++l)
            s += AL[a * LAT + l] * msg_w1[hc * 320 + 256 + l];
        VT[idx] = s;
    }
    // Qy[a][j] = query_b[j] + sum_l AL[a][l] * query_w[j][l]
    for (int idx = tid; idx < NA * ATTD; idx += nth) {
        const int a = idx >> 6, j = idx & 63;
        float s = query_b[j];
        #pragma unroll 16
        for (int l = 0; l < LAT; ++l)
            s += AL[a * LAT + l] * query_w[j * LAT + l];
        Qy[idx] = s;
    }
}

__global__ __launch_bounds__(256) void main_kernel(
    const float* __restrict__ h,        // [16384][256]
    const float* __restrict__ AL,       // [32][64]
    const float* __restrict__ q_fc_b,   // [64]
    const float* __restrict__ msg_w2,   // [32][256]
    const float* __restrict__ msg_b2,   // [32]
    const float* __restrict__ key_b,    // [64]
    const float* __restrict__ ws,
    float* __restrict__ out)            // [16384][32]
{
    __shared__ unsigned short hbuf[TBR * KP];  // 16896 B (bf16 h tile)
    __shared__ float Zl[TBR * ZP];             // 49664 B (U | role_key | key -> S)
    __shared__ float Scl[TBR * NA];            // 4096 B  (scores)  total ~70.7 KB -> 2 blk/CU

    const int t  = threadIdx.x;
    const int b0 = blockIdx.x * TBR;
    const unsigned short* Wb = (const unsigned short*)ws;
    const float* VT = ws + WS_VT;
    const float* Qy = ws + WS_QY;

    // ---- stage h tile -> bf16 LDS (coalesced 32B reads, 16B LDS writes) ----
    for (int g = t; g < TBR * 32; g += 256) {
        const int row = g >> 5, kc = (g & 31) << 3;
        const float4* p = (const float4*)(h + (size_t)(b0 + row) * RNN + kc);
        const float4 v0 = p[0], v1 = p[1];
        ushort8 u;
        u[0] = f2bf(v0.x); u[1] = f2bf(v0.y); u[2] = f2bf(v0.z); u[3] = f2bf(v0.w);
        u[4] = f2bf(v1.x); u[5] = f2bf(v1.y); u[6] = f2bf(v1.z); u[7] = f2bf(v1.w);
        *(ushort8*)(hbuf + row * KP + kc) = u;
    }
    __syncthreads();

    // ---- MFMA GEMM: Z[32][384] = h_tile @ W^T  (A from LDS, B direct from global/L2) ----
    const int lane = t & 63, w = t >> 6;
    const int ln = lane & 15, quad = lane >> 4;
    f32x4 acc[2][6];
    #pragma unroll
    for (int mt = 0; mt < 2; ++mt)
        #pragma unroll
        for (int nt = 0; nt < 6; ++nt)
            acc[mt][nt] = (f32x4){0.f, 0.f, 0.f, 0.f};

    const short* hb  = (const short*)hbuf;
    const short* WBs = (const short*)Wb;
    #pragma unroll
    for (int kk = 0; kk < 8; ++kk) {
        const int ko = kk * 32 + quad * 8;
        const bf16x8 a0 = *(const bf16x8*)(hb + ln * KP + ko);
        const bf16x8 a1 = *(const bf16x8*)(hb + (ln + 16) * KP + ko);
        #pragma unroll
        for (int nt = 0; nt < 6; ++nt) {
            const int col = (w * 6 + nt) * 16 + ln;
            const bf16x8 bfr = *(const bf16x8*)(WBs + col * KP + ko);
            acc[0][nt] = __builtin_amdgcn_mfma_f32_16x16x32_bf16(a0, bfr, acc[0][nt], 0, 0, 0);
            acc[1][nt] = __builtin_amdgcn_mfma_f32_16x16x32_bf16(a1, bfr, acc[1][nt], 0, 0, 0);
        }
    }
    // C/D layout: col = lane&15, row = quad*4 + reg  [m89-verified]
    #pragma unroll
    for (int nt = 0; nt < 6; ++nt) {
        const int col = (w * 6 + nt) * 16 + ln;
        float bias = 0.f;
        if (col >= 320)      bias = key_b[col - 320];
        else if (col >= 256) bias = q_fc_b[col - 256];
        #pragma unroll
        for (int mt = 0; mt < 2; ++mt)
            #pragma unroll
            for (int r = 0; r < 4; ++r)
                Zl[(mt * 16 + quad * 4 + r) * ZP + col] = acc[mt][nt][r] + bias;
    }
    __syncthreads();

    // ---- S[b][hc] = sum_a leaky(U[b][hc] + V[a][hc]); thread t owns column hc=t ----
    {
        float vt[32];
        const float4* vp = (const float4*)(VT + t * NA);
        #pragma unroll
        for (int i = 0; i < 8; ++i) {
            const float4 v = vp[i];
            vt[4 * i] = v.x; vt[4 * i + 1] = v.y; vt[4 * i + 2] = v.z; vt[4 * i + 3] = v.w;
        }
        #pragma unroll
        for (int half = 0; half < 2; ++half) {
            float u[16], s[16];
            #pragma unroll
            for (int r = 0; r < 16; ++r) {
                u[r] = Zl[(half * 16 + r) * ZP + t];
                s[r] = 0.f;
            }
            #pragma unroll
            for (int a = 0; a < 32; ++a) {
                const float v = vt[a];
                #pragma unroll
                for (int r = 0; r < 16; ++r) {
                    const float pre = u[r] + v;
                    s[r] += (pre >= 0.f) ? pre : SLOPE * pre;
                }
            }
            #pragma unroll
            for (int r = 0; r < 16; ++r)
                Zl[(half * 16 + r) * ZP + t] = s[r];
        }
    }
    __syncthreads();

    // ---- scores[b][a] = (key[b] . Qy[a]) / 8 ----
    for (int p = t; p < TBR * NA; p += 256) {
        const int b = p >> 5, a = p & 31;
        const float4* kr = (const float4*)(Zl + b * ZP + 320);
        const float4* qr = (const float4*)(Qy + a * ATTD);
        float s = 0.f;
        #pragma unroll
        for (int j = 0; j < 16; ++j) {
            const float4 kv = kr[j], qv = qr[j];
            s += kv.x * qv.x + kv.y * qv.y + kv.z * qv.z + kv.w * qv.w;
        }
        Scl[p] = s * 0.125f;
    }
    __syncthreads();

    // ---- softmax + q + msgsum -> out ----
    for (int p = t; p < TBR * NA; p += 256) {
        const int b = p >> 5, a = p & 31;
        const float* srow = Scl + b * NA;
        float mx = -1e30f;
        #pragma unroll
        for (int i = 0; i < NA; ++i) mx = fmaxf(mx, srow[i]);
        float den = 0.f;
        #pragma unroll
        for (int i = 0; i < NA; ++i) den += __expf(srow[i] - mx);
        const float sm = __expf(srow[a] - mx) / den;

        const float4* rk = (const float4*)(Zl + b * ZP + 256);
        const float4* al = (const float4*)(AL + a * LAT);
        float qv = 0.f;
        #pragma unroll
        for (int j = 0; j < 16; ++j) {
            const float4 kv = rk[j], av = al[j];
            qv += kv.x * av.x + kv.y * av.y + kv.z * av.z + kv.w * av.w;
        }

        const float4* Sr  = (const float4*)(Zl + b * ZP);
        const float4* w2r = (const float4*)(msg_w2 + a * HID);
        float ms = 32.f * msg_b2[a];
        #pragma unroll
        for (int j = 0; j < 64; ++j) {
            const float4 sv = Sr[j], wv = w2r[j];
            ms += sv.x * wv.x + sv.y * wv.y + sv.z * wv.z + sv.w * wv.w;
        }
        out[(size_t)(b0 + b) * NA + a] = qv + sm * ms;
    }
}

extern "C" void kernel_launch(void* const* d_in, const int* in_sizes, int n_in,
                              void* d_out, int out_size, void* d_ws, size_t ws_size,
                              hipStream_t stream) {
    const float* h        = (const float*)d_in[0];
    const float* AL       = (const float*)d_in[1];
    const float* q_fc_w   = (const float*)d_in[2];
    const float* q_fc_b   = (const float*)d_in[3];
    const float* msg_w1   = (const float*)d_in[4];
    const float* msg_b1   = (const float*)d_in[5];
    const float* msg_w2   = (const float*)d_in[6];
    const float* msg_b2   = (const float*)d_in[7];
    const float* key_w    = (const float*)d_in[8];
    const float* key_b    = (const float*)d_in[9];
    const float* query_w  = (const float*)d_in[10];
    const float* query_b  = (const float*)d_in[11];
    float* out = (float*)d_out;
    float* ws  = (float*)d_ws;

    prep_kernel<<<128, 256, 0, stream>>>(AL, q_fc_w, msg_w1, msg_b1,
                                         key_w, query_w, query_b, ws);
    main_kernel<<<BB / TBR, 256, 0, stream>>>(h, AL, q_fc_b, msg_w2, msg_b2,
                                              key_b, ws, out);
}

// Round 3
// 125.042 us; speedup vs baseline: 2.8301x; 1.4781x over previous
//
#include <hip/hip_runtime.h>
#include <math.h>

// Problem constants (fixed by reference)
#define BB    16384
#define RNN   256
#define LAT   64
#define ATTD  64
#define NA    32
#define HID   256
#define NCOL  384
#define TBR   16       // rows per block -> grid 1024, 4 blocks/CU co-resident
#define KP    264      // bf16 K-stride (hbuf, Wb, Sb): 528B rows, 16B aligned
#define RKP   72       // bf16 K-stride for rk/key LDS tiles
#define SLOPE 0.01f

// ws layout (float-unit offsets):
//   Wb  bf16[384][264] @ 0       concat w1_h|q_fc_w|key_w, [col][k] (B-operand, n-major)
//   VT  f32 [256][32]  @ 50688   VT[hc][a] = msg_b1[hc] + AL[a].w1_a[hc]
//   W2b bf16[32][256]  @ 58880   msg_w2 bf16 (B-operand for msgsum MFMA)
//   ALb bf16[32][64]   @ 62976   action_latent bf16 (B-operand for q MFMA)
//   Qyb bf16[32][64]   @ 64000   0.125*(AL@query_w.T+query_b) bf16 (B-operand, scale folded)
#define WS_VT 50688
#define WS_W2 58880
#define WS_AL 62976
#define WS_QY 64000

typedef __attribute__((ext_vector_type(8))) short bf16x8;
typedef __attribute__((ext_vector_type(4))) float f32x4;
typedef __attribute__((ext_vector_type(8))) unsigned short ushort8;

__device__ __forceinline__ unsigned short f2bf(float x) {
    union { float f; unsigned u; } c; c.f = x;
    unsigned r = c.u + 0x7FFFu + ((c.u >> 16) & 1u);
    return (unsigned short)(r >> 16);
}

__global__ __launch_bounds__(256) void prep_kernel(
    const float* __restrict__ AL,       // [32][64]
    const float* __restrict__ q_fc_w,   // [64][256]
    const float* __restrict__ msg_w1,   // [256][320]
    const float* __restrict__ msg_b1,   // [256]
    const float* __restrict__ msg_w2,   // [32][256]
    const float* __restrict__ key_w,    // [64][256]
    const float* __restrict__ query_w,  // [64][64]
    const float* __restrict__ query_b,  // [64]
    float* __restrict__ ws)
{
    const int tid = blockIdx.x * 256 + threadIdx.x;
    const int nth = gridDim.x * 256;
    unsigned short* Wb  = (unsigned short*)ws;
    float*          VT  = ws + WS_VT;
    unsigned short* W2b = (unsigned short*)(ws + WS_W2);
    unsigned short* ALb = (unsigned short*)(ws + WS_AL);
    unsigned short* Qyb = (unsigned short*)(ws + WS_QY);

    // Wb[j][k]
    for (int idx = tid; idx < NCOL * 256; idx += nth) {
        const int j = idx >> 8, k = idx & 255;
        float v;
        if (j < 256)      v = msg_w1[j * 320 + k];
        else if (j < 320) v = q_fc_w[(j - 256) * 256 + k];
        else              v = key_w[(j - 320) * 256 + k];
        Wb[j * KP + k] = f2bf(v);
    }
    // VT[hc][a]
    for (int idx = tid; idx < HID * NA; idx += nth) {
        const int hc = idx >> 5, a = idx & 31;
        float s = msg_b1[hc];
        #pragma unroll 16
        for (int l = 0; l < LAT; ++l)
            s += AL[a * LAT + l] * msg_w1[hc * 320 + 256 + l];
        VT[idx] = s;
    }
    // W2b, ALb bf16 copies
    for (int idx = tid; idx < NA * HID; idx += nth)
        W2b[idx] = f2bf(msg_w2[idx]);
    for (int idx = tid; idx < NA * LAT; idx += nth)
        ALb[idx] = f2bf(AL[idx]);
    // Qyb[a][j] = 0.125*(query_b[j] + AL[a].query_w[j])
    for (int idx = tid; idx < NA * ATTD; idx += nth) {
        const int a = idx >> 6, j = idx & 63;
        float s = query_b[j];
        #pragma unroll 16
        for (int l = 0; l < LAT; ++l)
            s += AL[a * LAT + l] * query_w[j * LAT + l];
        Qyb[idx] = f2bf(0.125f * s);
    }
}

__global__ __launch_bounds__(256, 4) void main_kernel(
    const float* __restrict__ h,        // [16384][256]
    const float* __restrict__ q_fc_b,   // [64]
    const float* __restrict__ msg_b2,   // [32]
    const float* __restrict__ key_b,    // [64]
    const float* __restrict__ ws,
    float* __restrict__ out)            // [16384][32]
{
    __shared__ unsigned short hbuf[TBR * KP];   // 8448 B  bf16 h tile (A-operand, GEMM1)
    __shared__ unsigned short Sb[TBR * KP];     // 8448 B  bf16 S tile (A-operand, msgsum)
    __shared__ unsigned short rkb[TBR * RKP];   // 2304 B  bf16 role_key (A-operand, q)
    __shared__ unsigned short keyb[TBR * RKP];  // 2304 B  bf16 key (A-operand, scores)
    __shared__ float Scl[TBR * 33];             // 2112 B  scores fp32
    __shared__ float ql[TBR * 33];              // 2112 B  q fp32
    __shared__ float stat_mx[TBR], stat_rd[TBR];
    // total ~25.9 KB -> LDS allows 6 blocks/CU; VGPR<=128 -> 4 blocks/CU

    const int t  = threadIdx.x;
    const int b0 = blockIdx.x * TBR;
    const short* Wbs = (const short*)ws;
    const float* VTf = ws + WS_VT;
    const short* W2s = (const short*)(ws + WS_W2);
    const short* ALs = (const short*)(ws + WS_AL);
    const short* Qys = (const short*)(ws + WS_QY);

    // ---- stage h tile -> bf16 LDS ----
    for (int g = t; g < TBR * 32; g += 256) {
        const int row = g >> 5, kc = (g & 31) << 3;
        const float4* p = (const float4*)(h + (size_t)(b0 + row) * RNN + kc);
        const float4 v0 = p[0], v1 = p[1];
        ushort8 u;
        u[0] = f2bf(v0.x); u[1] = f2bf(v0.y); u[2] = f2bf(v0.z); u[3] = f2bf(v0.w);
        u[4] = f2bf(v1.x); u[5] = f2bf(v1.y); u[6] = f2bf(v1.z); u[7] = f2bf(v1.w);
        *(ushort8*)(hbuf + row * KP + kc) = u;
    }
    __syncthreads();

    const int lane = t & 63, w = t >> 6;
    const int ln = lane & 15, quad = lane >> 4;

    // ---- GEMM1: Z[16][384] = h_tile @ W^T; wave w owns cols w*96..w*96+95 ----
    f32x4 acc[6];
    #pragma unroll
    for (int nt = 0; nt < 6; ++nt) acc[nt] = (f32x4){0.f, 0.f, 0.f, 0.f};
    const short* hb = (const short*)hbuf;
    #pragma unroll
    for (int kk = 0; kk < 8; ++kk) {
        const int ko = kk * 32 + quad * 8;
        const bf16x8 af = *(const bf16x8*)(hb + ln * KP + ko);
        #pragma unroll
        for (int nt = 0; nt < 6; ++nt) {
            const int col = (w * 6 + nt) * 16 + ln;
            const bf16x8 bfr = *(const bf16x8*)(Wbs + col * KP + ko);
            acc[nt] = __builtin_amdgcn_mfma_f32_16x16x32_bf16(af, bfr, acc[nt], 0, 0, 0);
        }
    }

    // ---- per-column post-processing in C-registers (col=lane&15, row=quad*4+r) ----
    #pragma unroll
    for (int nt = 0; nt < 6; ++nt) {
        const int colbase = (w * 6 + nt) * 16;     // wave-uniform
        const int col = colbase + ln;
        if (colbase < 256) {
            // S column: S[row][col] = sum_a leaky(U + VT[col][a])
            float vt[32];
            const float4* vp = (const float4*)(VTf + col * NA);
            #pragma unroll
            for (int i = 0; i < 8; ++i) {
                const float4 v = vp[i];
                vt[4*i] = v.x; vt[4*i+1] = v.y; vt[4*i+2] = v.z; vt[4*i+3] = v.w;
            }
            #pragma unroll
            for (int r = 0; r < 4; ++r) {
                const float u = acc[nt][r];
                float s = 0.f;
                #pragma unroll
                for (int a = 0; a < 32; ++a) {
                    const float pre = u + vt[a];
                    s += fmaxf(pre, SLOPE * pre);   // leaky = max(x, 0.01x)
                }
                Sb[(quad * 4 + r) * KP + col] = f2bf(s);
            }
        } else if (colbase < 320) {
            const int k = col - 256;
            const float bias = q_fc_b[k];
            #pragma unroll
            for (int r = 0; r < 4; ++r)
                rkb[(quad * 4 + r) * RKP + k] = f2bf(acc[nt][r] + bias);
        } else {
            const int k = col - 320;
            const float bias = key_b[k];
            #pragma unroll
            for (int r = 0; r < 4; ++r)
                keyb[(quad * 4 + r) * RKP + k] = f2bf(acc[nt][r] + bias);
        }
    }
    __syncthreads();

    // ---- second MFMA round ----
    f32x4 mc = (f32x4){0.f, 0.f, 0.f, 0.f};
    if (w < 2) {
        // msgsum: S[16][256] @ w2^T -> C[16 rows][a-half w]
        const short* Sbs = (const short*)Sb;
        #pragma unroll
        for (int kk = 0; kk < 8; ++kk) {
            const int ko = kk * 32 + quad * 8;
            const bf16x8 af = *(const bf16x8*)(Sbs + ln * KP + ko);
            const bf16x8 bfr = *(const bf16x8*)(W2s + (w * 16 + ln) * HID + ko);
            mc = __builtin_amdgcn_mfma_f32_16x16x32_bf16(af, bfr, mc, 0, 0, 0);
        }
    } else {
        // q = rk @ AL^T and scores = key @ (Qy/8)^T -> a-half (w-2)
        const int na = w - 2;
        f32x4 qc = (f32x4){0.f, 0.f, 0.f, 0.f};
        f32x4 sc = (f32x4){0.f, 0.f, 0.f, 0.f};
        const short* rks = (const short*)rkb;
        const short* kys = (const short*)keyb;
        #pragma unroll
        for (int kk = 0; kk < 2; ++kk) {
            const int ko = kk * 32 + quad * 8;
            const bf16x8 aq = *(const bf16x8*)(rks + ln * RKP + ko);
            const bf16x8 bq = *(const bf16x8*)(ALs + (na * 16 + ln) * LAT + ko);
            qc = __builtin_amdgcn_mfma_f32_16x16x32_bf16(aq, bq, qc, 0, 0, 0);
            const bf16x8 ak = *(const bf16x8*)(kys + ln * RKP + ko);
            const bf16x8 bk = *(const bf16x8*)(Qys + (na * 16 + ln) * LAT + ko);
            sc = __builtin_amdgcn_mfma_f32_16x16x32_bf16(ak, bk, sc, 0, 0, 0);
        }
        const int a = na * 16 + ln;
        #pragma unroll
        for (int r = 0; r < 4; ++r) {
            ql [(quad * 4 + r) * 33 + a] = qc[r];
            Scl[(quad * 4 + r) * 33 + a] = sc[r];
        }
    }
    __syncthreads();

    // ---- row softmax stats (16 threads) ----
    if (t < TBR) {
        const float* srow = Scl + t * 33;
        float mx = -1e30f;
        #pragma unroll
        for (int i = 0; i < NA; ++i) mx = fmaxf(mx, srow[i]);
        float den = 0.f;
        #pragma unroll
        for (int i = 0; i < NA; ++i) den += __expf(srow[i] - mx);
        stat_mx[t] = mx;
        stat_rd[t] = 1.f / den;
    }
    __syncthreads();

    // ---- combine + store (waves 0,1 hold msg C-tiles) ----
    if (w < 2) {
        const int a = w * 16 + ln;
        const float b2 = 32.f * msg_b2[a];
        #pragma unroll
        for (int r = 0; r < 4; ++r) {
            const int row = quad * 4 + r;
            const float sm = __expf(Scl[row * 33 + a] - stat_mx[row]) * stat_rd[row];
            out[(size_t)(b0 + row) * NA + a] = ql[row * 33 + a] + sm * (mc[r] + b2);
        }
    }
}

extern "C" void kernel_launch(void* const* d_in, const int* in_sizes, int n_in,
                              void* d_out, int out_size, void* d_ws, size_t ws_size,
                              hipStream_t stream) {
    const float* h        = (const float*)d_in[0];
    const float* AL       = (const float*)d_in[1];
    const float* q_fc_w   = (const float*)d_in[2];
    const float* q_fc_b   = (const float*)d_in[3];
    const float* msg_w1   = (const float*)d_in[4];
    const float* msg_b1   = (const float*)d_in[5];
    const float* msg_w2   = (const float*)d_in[6];
    const float* msg_b2   = (const float*)d_in[7];
    const float* key_w    = (const float*)d_in[8];
    const float* key_b    = (const float*)d_in[9];
    const float* query_w  = (const float*)d_in[10];
    const float* query_b  = (const float*)d_in[11];
    float* out = (float*)d_out;
    float* ws  = (float*)d_ws;

    prep_kernel<<<128, 256, 0, stream>>>(AL, q_fc_w, msg_w1, msg_b1, msg_w2,
                                         key_w, query_w, query_b, ws);
    main_kernel<<<BB / TBR, 256, 0, stream>>>(h, q_fc_b, msg_b2, key_b, ws, out);
}